// Round 7
// baseline (417.645 us; speedup 1.0000x reference)
//
#include <hip/hip_runtime.h>
#include <stdint.h>

#define N_TOK 2048
#define H_DIM 1024
#define F_DIM 2816
#define N_EXP 8
#define NSLOT (N_TOK * 2)

#define BK 64
#define KSPLIT 2
#define KHALF (F_DIM / KSPLIT)   // 1408
#define MAX_TILES 40             // sum_e ceil(cnt_e/128) <= 32 + 7 remainder tiles

typedef __attribute__((ext_vector_type(8))) short bf16x8;
typedef __attribute__((ext_vector_type(4))) float f32x4;

typedef __attribute__((address_space(1))) unsigned int gu32;
typedef __attribute__((address_space(3))) unsigned int lu32;

static __device__ __forceinline__ unsigned short f2bf(float f) {
    union { float f; unsigned u; } v; v.f = f;
    unsigned r = v.u + 0x7fffu + ((v.u >> 16) & 1u);   // round-to-nearest-even
    return (unsigned short)(r >> 16);
}

// async 16B/lane global->LDS; LDS dest must be wave-uniform base (lane*16 implicit)
static __device__ __forceinline__ void gload16(const unsigned short* g, unsigned short* l) {
    __builtin_amdgcn_global_load_lds((const gu32*)g, (lu32*)l, 16, 0, 0);
}

// ---------------- Convert (+ folded scan): fp32 -> bf16 for w1, w2 ------------
__global__ __launch_bounds__(256) void convert_w_kernel(
    const float* __restrict__ w1, const float* __restrict__ w2,
    unsigned short* __restrict__ w1_bf, unsigned short* __restrict__ w2_bf,
    const int* __restrict__ counts, int* __restrict__ offsets,
    int* __restrict__ tile_e, int* __restrict__ tile_m, int* __restrict__ ntiles)
{
    // folded scan: outputs consumed only by later kernels (stream-ordered)
    if (blockIdx.x == 0 && threadIdx.x == 0) {
        int acc = 0, t = 0;
        for (int e = 0; e < N_EXP; e++) {
            offsets[e] = acc; acc += counts[e];
            const int nt = (counts[e] + 127) >> 7;
            for (int m = 0; m < nt; m++) { tile_e[t] = e; tile_m[t] = m; t++; }
        }
        *ntiles = t;
    }

    const long NU4 = (long)N_EXP * F_DIM * H_DIM / 4;   // float4 units per tensor
    const long total = 2 * NU4;
    long u = (long)blockIdx.x * 256 + threadIdx.x;
    const long stride = (long)gridDim.x * 256;
    // 2 independent units per iteration: both loads issued before either store
    for (; u + stride < total; u += 2 * stride) {
        const long u1 = u + stride;
        const float* s0 = (u  < NU4) ? w1 : w2;
        const float* s1 = (u1 < NU4) ? w1 : w2;
        unsigned short* d0 = (u  < NU4) ? w1_bf : w2_bf;
        unsigned short* d1 = (u1 < NU4) ? w1_bf : w2_bf;
        const long k0 = (u  < NU4) ? u  : u  - NU4;
        const long k1 = (u1 < NU4) ? u1 : u1 - NU4;
        const float4 v0 = *(const float4*)(s0 + k0 * 4);
        const float4 v1 = *(const float4*)(s1 + k1 * 4);
        uint2 o0, o1;
        o0.x = (unsigned)f2bf(v0.x) | ((unsigned)f2bf(v0.y) << 16);
        o0.y = (unsigned)f2bf(v0.z) | ((unsigned)f2bf(v0.w) << 16);
        o1.x = (unsigned)f2bf(v1.x) | ((unsigned)f2bf(v1.y) << 16);
        o1.y = (unsigned)f2bf(v1.z) | ((unsigned)f2bf(v1.w) << 16);
        *(uint2*)(d0 + k0 * 4) = o0;
        *(uint2*)(d1 + k1 * 4) = o1;
    }
    if (u < total) {
        const float* s = (u < NU4) ? w1 : w2;
        unsigned short* d = (u < NU4) ? w1_bf : w2_bf;
        const long k = (u < NU4) ? u : u - NU4;
        const float4 v = *(const float4*)(s + k * 4);
        uint2 o;
        o.x = (unsigned)f2bf(v.x) | ((unsigned)f2bf(v.y) << 16);
        o.y = (unsigned)f2bf(v.z) | ((unsigned)f2bf(v.w) << 16);
        *(uint2*)(d + k * 4) = o;
    }
}

// ---------------- Router: 1 wave per token; also emits x_bf -------------------
__global__ __launch_bounds__(256) void router_kernel(
    const float* __restrict__ x, const float* __restrict__ gate_w,
    int* __restrict__ counts, int* __restrict__ row_token, float* __restrict__ row_weight,
    int* __restrict__ slot_e, int* __restrict__ slot_pos,
    unsigned short* __restrict__ x_bf)
{
    __shared__ float gsm[N_EXP * H_DIM];
    for (int i = threadIdx.x; i < N_EXP * H_DIM / 4; i += 256)
        ((float4*)gsm)[i] = ((const float4*)gate_w)[i];
    __syncthreads();

    const int wave = threadIdx.x >> 6;
    const int lane = threadIdx.x & 63;
    const int n = blockIdx.x * 4 + wave;
    if (n >= N_TOK) return;

    const float4* xrow = (const float4*)(x + (size_t)n * H_DIM);
    float4 xv[4];
#pragma unroll
    for (int i = 0; i < 4; i++) xv[i] = xrow[lane + 64 * i];

    // fused x -> bf16
#pragma unroll
    for (int i = 0; i < 4; i++) {
        ushort4 b;
        b.x = f2bf(xv[i].x); b.y = f2bf(xv[i].y); b.z = f2bf(xv[i].z); b.w = f2bf(xv[i].w);
        *(ushort4*)(x_bf + (size_t)n * H_DIM + (lane + 64 * i) * 4) = b;
    }

    float logit[N_EXP];
#pragma unroll
    for (int e = 0; e < N_EXP; e++) {
        float p = 0.f;
#pragma unroll
        for (int i = 0; i < 4; i++) {
            const float4 g = ((const float4*)gsm)[e * 256 + lane + 64 * i];
            p += xv[i].x * g.x + xv[i].y * g.y + xv[i].z * g.z + xv[i].w * g.w;
        }
#pragma unroll
        for (int s = 32; s > 0; s >>= 1) p += __shfl_xor(p, s, 64);
        logit[e] = p;
    }

    if (lane == 0) {
        int e0 = 0; float l0 = logit[0];
#pragma unroll
        for (int e = 1; e < N_EXP; e++) if (logit[e] > l0) { l0 = logit[e]; e0 = e; }
        int e1 = -1; float l1 = -3.4e38f;
#pragma unroll
        for (int e = 0; e < N_EXP; e++) if (e != e0 && logit[e] > l1) { l1 = logit[e]; e1 = e; }
        float w0 = 1.f / (1.f + __expf(l1 - l0));
        float w1 = 1.f - w0;
        int p0 = atomicAdd(&counts[e0], 1);
        int p1 = atomicAdd(&counts[e1], 1);
        row_token[e0 * N_TOK + p0] = n;  row_weight[e0 * N_TOK + p0] = w0;
        row_token[e1 * N_TOK + p1] = n;  row_weight[e1 * N_TOK + p1] = w1;
        slot_e[n * 2 + 0] = e0;  slot_pos[n * 2 + 0] = p0;
        slot_e[n * 2 + 1] = e1;  slot_pos[n * 2 + 1] = p1;
    }
}

// ---------------- Up GEMM: 128x128, 2-phase dbuf (T3-min), compact tiles ------
// act = silu(X_gather @ w1[e]^T), bf16 out
__global__ __launch_bounds__(256) void up_gemm_kernel(
    const unsigned short* __restrict__ x_bf, const unsigned short* __restrict__ w1_bf,
    const int* __restrict__ counts, const int* __restrict__ offsets,
    const int* __restrict__ tile_e, const int* __restrict__ tile_m,
    const int* __restrict__ ntiles,
    const int* __restrict__ row_token,
    unsigned short* __restrict__ act)
{
    const int slot = blockIdx.y;
    if (slot >= *ntiles) return;
    const int e = tile_e[slot];
    const int mTile = tile_m[slot];
    const int cnt = counts[e];
    const int fTile = blockIdx.x;
    const int off = offsets[e];

    __shared__ __align__(16) unsigned short As[2][128 * 64];   // 2 x 16 KB
    __shared__ __align__(16) unsigned short Bs[2][128 * 64];   // 2 x 16 KB

    const int tid = threadIdx.x;
    const int lane = tid & 63;
    const int wave = tid >> 6;
    const int wm = (wave >> 1) * 64, wn = (wave & 1) * 64;

    // staging: 16 chunks of 1KB per matrix; wave w owns chunks w*4..w*4+3.
    // chunk c covers rows c*8..c*8+7; lane l -> row c*8+(l>>3), col elems (l&7)*8.
    const unsigned short* aSrc[4];
    const unsigned short* bSrc[4];
#pragma unroll
    for (int j = 0; j < 4; j++) {
        const int row_local = wave * 32 + j * 8 + (lane >> 3);
        const int pos = mTile * 128 + row_local;
        const int tok = row_token[e * N_TOK + min(pos, cnt - 1)];
        aSrc[j] = x_bf + (size_t)tok * H_DIM + (lane & 7) * 8;
        bSrc[j] = w1_bf + ((size_t)e * F_DIM + fTile * 128 + row_local) * H_DIM + (lane & 7) * 8;
    }

    f32x4 acc[4][4];
#pragma unroll
    for (int i = 0; i < 4; i++)
#pragma unroll
        for (int j = 0; j < 4; j++) acc[i][j] = (f32x4)(0.f);

    // prologue: stage tile 0 into buffer 0
#pragma unroll
    for (int j = 0; j < 4; j++) {
        gload16(aSrc[j], &As[0][(wave * 4 + j) * 512]);
        gload16(bSrc[j], &Bs[0][(wave * 4 + j) * 512]);
    }
    __syncthreads();

    const int NKT = H_DIM / BK;   // 16
    for (int kt = 0; kt < NKT; kt++) {
        const int cur = kt & 1;
        // issue next tile's loads into the other buffer; they fly under the MFMAs
        if (kt + 1 < NKT) {
            const int koff = (kt + 1) * BK;
#pragma unroll
            for (int j = 0; j < 4; j++) {
                gload16(aSrc[j] + koff, &As[cur ^ 1][(wave * 4 + j) * 512]);
                gload16(bSrc[j] + koff, &Bs[cur ^ 1][(wave * 4 + j) * 512]);
            }
        }
        __builtin_amdgcn_s_setprio(1);
#pragma unroll
        for (int kk = 0; kk < BK / 32; kk++) {
            const int kloc = kk * 32 + (lane >> 4) * 8;
            bf16x8 af[4], bfr[4];
#pragma unroll
            for (int i = 0; i < 4; i++)
                af[i] = *(const bf16x8*)(&As[cur][(wm + i * 16 + (lane & 15)) * 64 + kloc]);
#pragma unroll
            for (int i = 0; i < 4; i++)
                bfr[i] = *(const bf16x8*)(&Bs[cur][(wn + i * 16 + (lane & 15)) * 64 + kloc]);
#pragma unroll
            for (int i = 0; i < 4; i++)
#pragma unroll
                for (int j = 0; j < 4; j++)
                    acc[i][j] = __builtin_amdgcn_mfma_f32_16x16x32_bf16(af[i], bfr[j], acc[i][j], 0, 0, 0);
        }
        __builtin_amdgcn_s_setprio(0);
        // one barrier per K-step: drains this wave's stage (vmcnt) AFTER compute,
        // and guarantees all reads of buf[cur] done before it's overwritten next iter
        __syncthreads();
    }

    // epilogue: silu + bf16 store (C/D layout: col=lane&15, row=(lane>>4)*4+reg)
#pragma unroll
    for (int i = 0; i < 4; i++) {
        const int mrow = wm + i * 16 + ((lane >> 4) << 2);
#pragma unroll
        for (int r = 0; r < 4; r++) {
            const int m = mTile * 128 + mrow + r;
            if (m < cnt) {
#pragma unroll
                for (int j = 0; j < 4; j++) {
                    float v = acc[i][j][r];
                    float s = v / (1.f + __expf(-v));
                    int col = fTile * 128 + wn + j * 16 + (lane & 15);
                    act[(size_t)(off + m) * F_DIM + col] = f2bf(s);
                }
            }
        }
    }
}

// ---------------- Down GEMM: 128x128, 2-phase dbuf, split-K=2 -----------------
__global__ __launch_bounds__(256) void down_gemm_kernel(
    const unsigned short* __restrict__ act, const unsigned short* __restrict__ w2_bf,
    const int* __restrict__ counts, const int* __restrict__ offsets,
    const int* __restrict__ tile_e, const int* __restrict__ tile_m,
    const int* __restrict__ ntiles,
    const float* __restrict__ row_weight,
    float* __restrict__ out_partial)   // [KSPLIT][NSLOT][H_DIM]
{
    const int slot = blockIdx.y;
    if (slot >= *ntiles) return;
    const int e = tile_e[slot];
    const int mTile = tile_m[slot];
    const int ks = blockIdx.z;
    const int cnt = counts[e];
    const int hTile = blockIdx.x;
    const int off = offsets[e];
    const int kbase = ks * KHALF;

    __shared__ __align__(16) unsigned short As[2][128 * 64];
    __shared__ __align__(16) unsigned short Bs[2][128 * 64];

    const int tid = threadIdx.x;
    const int lane = tid & 63;
    const int wave = tid >> 6;
    const int wm = (wave >> 1) * 64, wn = (wave & 1) * 64;

    const unsigned short* aSrc[4];
    const unsigned short* bSrc[4];
#pragma unroll
    for (int j = 0; j < 4; j++) {
        const int row_local = wave * 32 + j * 8 + (lane >> 3);
        const int slotRow = off + min(mTile * 128 + row_local, cnt - 1);
        aSrc[j] = act + (size_t)slotRow * F_DIM + kbase + (lane & 7) * 8;
        bSrc[j] = w2_bf + ((size_t)e * H_DIM + hTile * 128 + row_local) * F_DIM + kbase + (lane & 7) * 8;
    }

    f32x4 acc[4][4];
#pragma unroll
    for (int i = 0; i < 4; i++)
#pragma unroll
        for (int j = 0; j < 4; j++) acc[i][j] = (f32x4)(0.f);

    // prologue
#pragma unroll
    for (int j = 0; j < 4; j++) {
        gload16(aSrc[j], &As[0][(wave * 4 + j) * 512]);
        gload16(bSrc[j], &Bs[0][(wave * 4 + j) * 512]);
    }
    __syncthreads();

    const int NKT = KHALF / BK;   // 22
    for (int kt = 0; kt < NKT; kt++) {
        const int cur = kt & 1;
        if (kt + 1 < NKT) {
            const int koff = (kt + 1) * BK;
#pragma unroll
            for (int j = 0; j < 4; j++) {
                gload16(aSrc[j] + koff, &As[cur ^ 1][(wave * 4 + j) * 512]);
                gload16(bSrc[j] + koff, &Bs[cur ^ 1][(wave * 4 + j) * 512]);
            }
        }
        __builtin_amdgcn_s_setprio(1);
#pragma unroll
        for (int kk = 0; kk < BK / 32; kk++) {
            const int kloc = kk * 32 + (lane >> 4) * 8;
            bf16x8 af[4], bfr[4];
#pragma unroll
            for (int i = 0; i < 4; i++)
                af[i] = *(const bf16x8*)(&As[cur][(wm + i * 16 + (lane & 15)) * 64 + kloc]);
#pragma unroll
            for (int i = 0; i < 4; i++)
                bfr[i] = *(const bf16x8*)(&Bs[cur][(wn + i * 16 + (lane & 15)) * 64 + kloc]);
#pragma unroll
            for (int i = 0; i < 4; i++)
#pragma unroll
                for (int j = 0; j < 4; j++)
                    acc[i][j] = __builtin_amdgcn_mfma_f32_16x16x32_bf16(af[i], bfr[j], acc[i][j], 0, 0, 0);
        }
        __builtin_amdgcn_s_setprio(0);
        __syncthreads();
    }

    float* obase = out_partial + (size_t)ks * NSLOT * H_DIM;
#pragma unroll
    for (int i = 0; i < 4; i++) {
        const int mrow = wm + i * 16 + ((lane >> 4) << 2);
#pragma unroll
        for (int r = 0; r < 4; r++) {
            const int m = mTile * 128 + mrow + r;
            if (m < cnt) {
                const float w = row_weight[e * N_TOK + m];
#pragma unroll
                for (int j = 0; j < 4; j++) {
                    int col = hTile * 128 + wn + j * 16 + (lane & 15);
                    obase[(size_t)(off + m) * H_DIM + col] = w * acc[i][j][r];
                }
            }
        }
    }
}

// ---------------- Combine: y[n] = sum over 2 slots x 2 K-splits ---------------
__global__ __launch_bounds__(256) void combine_kernel(
    const float* __restrict__ out_partial, const int* __restrict__ offsets,
    const int* __restrict__ slot_e, const int* __restrict__ slot_pos,
    float* __restrict__ out)
{
    const int n = blockIdx.x;
    const int r0 = offsets[slot_e[n * 2 + 0]] + slot_pos[n * 2 + 0];
    const int r1 = offsets[slot_e[n * 2 + 1]] + slot_pos[n * 2 + 1];
    const int t = threadIdx.x;
    const float* p0 = out_partial;
    const float* p1 = out_partial + (size_t)NSLOT * H_DIM;
    const float4 a = *(const float4*)(p0 + (size_t)r0 * H_DIM + t * 4);
    const float4 b = *(const float4*)(p1 + (size_t)r0 * H_DIM + t * 4);
    const float4 c = *(const float4*)(p0 + (size_t)r1 * H_DIM + t * 4);
    const float4 d = *(const float4*)(p1 + (size_t)r1 * H_DIM + t * 4);
    float4 s;
    s.x = (a.x + b.x) + (c.x + d.x);
    s.y = (a.y + b.y) + (c.y + d.y);
    s.z = (a.z + b.z) + (c.z + d.z);
    s.w = (a.w + b.w) + (c.w + d.w);
    *(float4*)(out + (size_t)n * H_DIM + t * 4) = s;
}

extern "C" void kernel_launch(void* const* d_in, const int* in_sizes, int n_in,
                              void* d_out, int out_size, void* d_ws, size_t ws_size,
                              hipStream_t stream) {
    const float* x      = (const float*)d_in[0];
    const float* gate_w = (const float*)d_in[1];
    const float* w1     = (const float*)d_in[2];
    const float* w2     = (const float*)d_in[3];
    float* out = (float*)d_out;

    char* ws = (char*)d_ws;
    size_t o = 0;
    auto alloc = [&](size_t bytes) -> void* {
        void* p = ws + o;
        o = (o + bytes + 255) & ~(size_t)255;
        return p;
    };
    int*   counts     = (int*)  alloc(N_EXP * sizeof(int));
    int*   offsets    = (int*)  alloc(N_EXP * sizeof(int));
    int*   tile_e     = (int*)  alloc(MAX_TILES * sizeof(int));
    int*   tile_m     = (int*)  alloc(MAX_TILES * sizeof(int));
    int*   ntiles     = (int*)  alloc(sizeof(int));
    int*   row_token  = (int*)  alloc((size_t)N_EXP * N_TOK * sizeof(int));
    float* row_weight = (float*)alloc((size_t)N_EXP * N_TOK * sizeof(float));
    int*   slot_e     = (int*)  alloc((size_t)N_TOK * 2 * sizeof(int));
    int*   slot_pos   = (int*)  alloc((size_t)N_TOK * 2 * sizeof(int));
    unsigned short* act = (unsigned short*)alloc((size_t)NSLOT * F_DIM * sizeof(unsigned short));
    float* out_partial = (float*)alloc((size_t)KSPLIT * NSLOT * H_DIM * sizeof(float));
    unsigned short* x_bf  = (unsigned short*)alloc((size_t)N_TOK * H_DIM * sizeof(unsigned short));
    unsigned short* w1_bf = (unsigned short*)alloc((size_t)N_EXP * F_DIM * H_DIM * sizeof(unsigned short));
    unsigned short* w2_bf = (unsigned short*)alloc((size_t)N_EXP * H_DIM * F_DIM * sizeof(unsigned short));

    hipMemsetAsync(counts, 0, N_EXP * sizeof(int), stream);

    router_kernel<<<N_TOK / 4, 256, 0, stream>>>(x, gate_w, counts, row_token, row_weight, slot_e, slot_pos, x_bf);
    convert_w_kernel<<<2048, 256, 0, stream>>>(w1, w2, w1_bf, w2_bf,
                                               counts, offsets, tile_e, tile_m, ntiles);
    up_gemm_kernel<<<dim3(F_DIM / 128, MAX_TILES), 256, 0, stream>>>(
        x_bf, w1_bf, counts, offsets, tile_e, tile_m, ntiles, row_token, act);
    down_gemm_kernel<<<dim3(H_DIM / 128, MAX_TILES, KSPLIT), 256, 0, stream>>>(
        act, w2_bf, counts, offsets, tile_e, tile_m, ntiles, row_weight, out_partial);
    combine_kernel<<<N_TOK, 256, 0, stream>>>(out_partial, offsets, slot_e, slot_pos, out);
}